// Round 7
// baseline (278.113 us; speedup 1.0000x reference)
//
#include <hip/hip_runtime.h>
#include <math.h>

#define BB 4
#define SS 4096
#define DD 2048
#define EE 64
#define KK 8
#define TT_TOTAL (BB*SS)      // 16384 tokens
#define E2 128                // stacked outputs (Wr 0..63, Wn 64..127)
#define DK 32                 // D-chunk
#define NC (DD/DK)

typedef double double2_t __attribute__((ext_vector_type(2)));
typedef double double4_t __attribute__((ext_vector_type(4)));

__device__ __forceinline__ double softplus64(double x) {
    return fmax(x, 0.0) + log1p(exp(-fabs(x)));
}

// LDS column swizzle: involution on bits 1..3 keyed by bits 4..6.
__device__ __forceinline__ int SW(int c) {
    return c ^ (((c >> 4) & 7) << 1);
}

// =====================================================================
// Primary GEMM: block tile 64 tok x 128 out, thread tile 4x8, f32 LDS,
// split-K. Math: f64 FMA ascending k (f32->f64 cvt exact) — z partials
// bit-identical to R6's verified kernel. grid = 256*KS, 256 threads.
// =====================================================================
#define XROWF 66    // 64 cols + 2 pad (264 B rows, 8B-aligned)
#define WROWF 130   // 128 cols + 2 pad (520 B rows, 8B-aligned)

template<int KS>
__launch_bounds__(256, 4)
__global__ void gemm64_kernel(const float* __restrict__ x,
                              const float* __restrict__ Wr,
                              const float* __restrict__ Wn,
                              double* __restrict__ zp)
{
    __shared__ __align__(16) float xs[DK][XROWF];   //  8448 B : xs[k][SW(tok)]
    __shared__ __align__(16) float ws[DK][WROWF];   // 16640 B : ws[k][SW(out)]

    const int tid   = threadIdx.x;
    const int split = blockIdx.x % KS;
    const int bt    = blockIdx.x / KS;
    const int tok0  = bt * 64;
    const int kbase = split * (DD / KS);
    const int NCH   = (DD / KS) / DK;

    // ---- staging mapping ----
    const int xrow = tid & 63;            // token row
    const int xkq  = tid >> 6;            // 0..3 -> k offset 8*xkq
    const int xc   = SW(xrow);
    const float* xsrc = x + (size_t)(tok0 + xrow) * DD + kbase + 8 * xkq;

    const int wrow = tid & 127;           // output row
    const int wkh  = tid >> 7;            // 0..1 -> k offset 16*wkh
    const int wc   = SW(wrow);
    const float* wsrc = ((wrow < EE) ? Wr + (size_t)wrow * DD
                                     : Wn + (size_t)(wrow - EE) * DD)
                        + kbase + 16 * wkh;

    // ---- compute mapping: toks {2tg2+e+32h}, outs {2og2+f+32g} ----
    const int og2 = tid & 15;
    const int tg2 = tid >> 4;             // 0..15
    const int cx0 = SW(2 * tg2);
    const int cx1 = SW(2 * tg2 + 32);
    int cw[4];
    #pragma unroll
    for (int g = 0; g < 4; ++g) cw[g] = SW(2 * og2 + 32 * g);

    double acc[4][8];
    #pragma unroll
    for (int t = 0; t < 4; ++t)
        #pragma unroll
        for (int o = 0; o < 8; ++o) acc[t][o] = 0.0;

    // preload chunk 0
    float4 xa[2], wa[4];
    #pragma unroll
    for (int i = 0; i < 2; ++i)
        xa[i] = *reinterpret_cast<const float4*>(xsrc + 4 * i);
    #pragma unroll
    for (int i = 0; i < 4; ++i)
        wa[i] = *reinterpret_cast<const float4*>(wsrc + 4 * i);

    for (int c = 0; c < NCH; ++c) {
        __syncthreads();   // previous chunk's reads done

        // stage to LDS (f32, transposed, SW-swizzled; 2-way writes = free)
        {
            const int kx = 8 * xkq;
            xs[kx+0][xc] = xa[0].x;  xs[kx+1][xc] = xa[0].y;
            xs[kx+2][xc] = xa[0].z;  xs[kx+3][xc] = xa[0].w;
            xs[kx+4][xc] = xa[1].x;  xs[kx+5][xc] = xa[1].y;
            xs[kx+6][xc] = xa[1].z;  xs[kx+7][xc] = xa[1].w;
            const int kw = 16 * wkh;
            #pragma unroll
            for (int i = 0; i < 4; ++i) {
                ws[kw + 4*i + 0][wc] = wa[i].x;
                ws[kw + 4*i + 1][wc] = wa[i].y;
                ws[kw + 4*i + 2][wc] = wa[i].z;
                ws[kw + 4*i + 3][wc] = wa[i].w;
            }
        }
        __syncthreads();

        // prefetch next chunk (lands under compute)
        if (c + 1 < NCH) {
            const int off = (c + 1) * DK;
            #pragma unroll
            for (int i = 0; i < 2; ++i)
                xa[i] = *reinterpret_cast<const float4*>(xsrc + off + 4 * i);
            #pragma unroll
            for (int i = 0; i < 4; ++i)
                wa[i] = *reinterpret_cast<const float4*>(wsrc + off + 4 * i);
        }

        // inner: per k, 6x ds_read_b64 + 12 cvt + 32 f64 FMA
        #pragma unroll 4
        for (int k = 0; k < DK; ++k) {
            const float2 xf0 = *reinterpret_cast<const float2*>(&xs[k][cx0]);
            const float2 xf1 = *reinterpret_cast<const float2*>(&xs[k][cx1]);
            float2 wf[4];
            #pragma unroll
            for (int g = 0; g < 4; ++g)
                wf[g] = *reinterpret_cast<const float2*>(&ws[k][cw[g]]);

            const double xv[4] = {(double)xf0.x, (double)xf0.y,
                                  (double)xf1.x, (double)xf1.y};
            double wv[8];
            #pragma unroll
            for (int g = 0; g < 4; ++g) {
                wv[2*g+0] = (double)wf[g].x;
                wv[2*g+1] = (double)wf[g].y;
            }
            #pragma unroll
            for (int t = 0; t < 4; ++t)
                #pragma unroll
                for (int o = 0; o < 8; ++o)
                    acc[t][o] = fma(xv[t], wv[o], acc[t][o]);
        }
    }

    // write partials: zp[split][tok][out]
    double* zbase = zp + (size_t)split * TT_TOTAL * E2;
    #pragma unroll
    for (int h = 0; h < 2; ++h)
        #pragma unroll
        for (int e = 0; e < 2; ++e) {
            const int tok = 2 * tg2 + e + 32 * h;
            double* row = zbase + (size_t)(tok0 + tok) * E2;
            #pragma unroll
            for (int g = 0; g < 4; ++g) {
                double2_t v = {acc[2*h+e][2*g+0], acc[2*h+e][2*g+1]};
                *reinterpret_cast<double2_t*>(&row[2 * og2 + 32 * g]) = v;
            }
        }
}

// =====================================================================
// topk over reduced partials (ascending split order = deterministic)
// =====================================================================
template<int KS>
__launch_bounds__(256, 4)
__global__ void topk2_kernel(const double* __restrict__ zp,
                             const float* __restrict__ bias,
                             const float* __restrict__ noise_u,
                             float* __restrict__ out_probs,
                             float* __restrict__ out_idx)
{
    const int tid  = threadIdx.x;
    const int wid  = tid >> 6;
    const int lane = tid & 63;
    const int tok0 = blockIdx.x * 32;

    for (int tt = 0; tt < 8; ++tt) {
        const int tok = tok0 + wid * 8 + tt;
        const size_t gtok = (size_t)tok;

        double logit = 0.0, noisy = 0.0;
        #pragma unroll
        for (int s = 0; s < KS; ++s) {
            const double* row = zp + (size_t)s * TT_TOTAL * E2 + (size_t)tok * E2;
            logit += row[lane];
            noisy += row[EE + lane];
        }
        const double zv = (double)noise_u[gtok * EE + lane] * softplus64(noisy)
                          + logit + (double)bias[lane];

        double zw = zv;
        bool   sel = false;
        double m0  = 0.0;
        #pragma unroll
        for (int it = 0; it < KK; ++it) {
            double v  = zw;
            int    ix = lane;
            #pragma unroll
            for (int off = 32; off > 0; off >>= 1) {
                const double ov = __shfl_xor(v, off, 64);
                const int    oi = __shfl_xor(ix, off, 64);
                if (ov > v || (ov == v && oi < ix)) { v = ov; ix = oi; }
            }
            if (it == 0) m0 = v;
            if (lane == ix) { sel = true; zw = -INFINITY; }
            if (lane == 0) out_idx[gtok * KK + it] = (float)ix;
        }

        const double ex = sel ? exp(zv - m0) : 0.0;
        double den = ex;
        #pragma unroll
        for (int off = 32; off > 0; off >>= 1) den += __shfl_xor(den, off, 64);

        out_probs[gtok * EE + lane] = (float)(ex / den);
    }
}

// =====================================================================
// Tier-B: verified R5 two-kernel path (16 MiB ws)
// =====================================================================
#define BT 32
#define XT 34
#define WT 66

__launch_bounds__(256, 4)
__global__ void gemm_kernel(const float* __restrict__ x,
                            const float* __restrict__ Wr,
                            const float* __restrict__ Wn,
                            double* __restrict__ zout)
{
    __shared__ __align__(16) double xs[DK][XT];
    __shared__ __align__(16) double ws[DK][WT];

    const int tid  = threadIdx.x;
    const int bt   = blockIdx.x >> 1;
    const int be   = blockIdx.x & 1;
    const int tok0 = bt * BT;
    const int e0   = be * 64;

    const int kk = tid & 31;
    const int tq = tid >> 5;
    const float* xsrc[4];
    const float* wsrc[8];
    #pragma unroll
    for (int j = 0; j < 4; ++j)
        xsrc[j] = x + (size_t)(tok0 + 4 * tq + j) * DD + kk;
    #pragma unroll
    for (int j = 0; j < 4; ++j) {
        const int e  = e0 + 4 * tq + j;
        const int e2 = e0 + 32 + 4 * tq + j;
        wsrc[j]     = ((e  < EE) ? Wr + (size_t)e * DD
                                 : Wn + (size_t)(e  - EE) * DD) + kk;
        wsrc[4 + j] = ((e2 < EE) ? Wr + (size_t)e2 * DD
                                 : Wn + (size_t)(e2 - EE) * DD) + kk;
    }

    const int og = tid & 15;
    const int tp = tid >> 4;

    double acc[2][4];
    #pragma unroll
    for (int t = 0; t < 2; ++t)
        #pragma unroll
        for (int i = 0; i < 4; ++i) acc[t][i] = 0.0;

    float xr[4], wr[8];
    #pragma unroll
    for (int j = 0; j < 4; ++j) xr[j] = xsrc[j][0];
    #pragma unroll
    for (int j = 0; j < 8; ++j) wr[j] = wsrc[j][0];

    for (int c = 0; c < NC; ++c) {
        __syncthreads();
        {
            double4_t xv = {(double)xr[0], (double)xr[1], (double)xr[2], (double)xr[3]};
            *reinterpret_cast<double4_t*>(&xs[kk][4 * tq]) = xv;
            double4_t w0 = {(double)wr[0], (double)wr[1], (double)wr[2], (double)wr[3]};
            *reinterpret_cast<double4_t*>(&ws[kk][4 * tq]) = w0;
            double4_t w1 = {(double)wr[4], (double)wr[5], (double)wr[6], (double)wr[7]};
            *reinterpret_cast<double4_t*>(&ws[kk][32 + 4 * tq]) = w1;
        }
        __syncthreads();
        if (c + 1 < NC) {
            const int off = (c + 1) * DK;
            #pragma unroll
            for (int j = 0; j < 4; ++j) xr[j] = xsrc[j][off];
            #pragma unroll
            for (int j = 0; j < 8; ++j) wr[j] = wsrc[j][off];
        }
        #pragma unroll 4
        for (int k = 0; k < DK; ++k) {
            const double2_t xv = *reinterpret_cast<const double2_t*>(&xs[k][2 * tp]);
            const double2_t w0 = *reinterpret_cast<const double2_t*>(&ws[k][2 * og]);
            const double2_t w1 = *reinterpret_cast<const double2_t*>(&ws[k][32 + 2 * og]);
            acc[0][0] = fma(xv.x, w0.x, acc[0][0]);
            acc[0][1] = fma(xv.x, w0.y, acc[0][1]);
            acc[0][2] = fma(xv.x, w1.x, acc[0][2]);
            acc[0][3] = fma(xv.x, w1.y, acc[0][3]);
            acc[1][0] = fma(xv.y, w0.x, acc[1][0]);
            acc[1][1] = fma(xv.y, w0.y, acc[1][1]);
            acc[1][2] = fma(xv.y, w1.x, acc[1][2]);
            acc[1][3] = fma(xv.y, w1.y, acc[1][3]);
        }
    }

    #pragma unroll
    for (int t = 0; t < 2; ++t) {
        const size_t base = (size_t)(tok0 + 2 * tp + t) * E2 + e0;
        double2_t lo = {acc[t][0], acc[t][1]};
        double2_t hi = {acc[t][2], acc[t][3]};
        *reinterpret_cast<double2_t*>(&zout[base + 2 * og])      = lo;
        *reinterpret_cast<double2_t*>(&zout[base + 32 + 2 * og]) = hi;
    }
}

// =====================================================================
// Tier-C: verified R4 monolithic kernel
// =====================================================================
#define F_XT 34
#define F_WR 130
#define F_ZR 130
#define F_SMEM ((DK*F_XT + DK*F_WR)*8)

__launch_bounds__(256, 3)
__global__ void router_kernel(const float* __restrict__ x,
                              const float* __restrict__ Wr,
                              const float* __restrict__ Wn,
                              const float* __restrict__ bias,
                              const float* __restrict__ noise_u,
                              float* __restrict__ out_probs,
                              float* __restrict__ out_idx)
{
    __shared__ __align__(16) char smem_raw[F_SMEM];
    double (*xs)[F_XT] = reinterpret_cast<double(*)[F_XT]>(smem_raw);
    double (*wt)[F_WR] = reinterpret_cast<double(*)[F_WR]>(smem_raw + DK*F_XT*8);
    double (*zbuf)[F_ZR] = reinterpret_cast<double(*)[F_ZR]>(smem_raw);

    const int tid  = threadIdx.x;
    const int tok0 = blockIdx.x * 32;
    const int stok = tid >> 3;
    const int sfi  = tid & 7;
    const float* xsrc = x + (size_t)(tok0 + stok) * DD + sfi * 4;
    const float* wsrc[4];
    #pragma unroll
    for (int it = 0; it < 4; ++it) {
        const int r = it * 32 + stok;
        wsrc[it] = ((r < EE) ? (Wr + (size_t)r * DD)
                             : (Wn + (size_t)(r - EE) * DD)) + sfi * 4;
    }
    const int tg = tid >> 5;
    const int eg = tid & 31;

    double acc[4][4];
    #pragma unroll
    for (int t = 0; t < 4; ++t)
        #pragma unroll
        for (int i = 0; i < 4; ++i) acc[t][i] = 0.0;

    float4 xr  = *reinterpret_cast<const float4*>(xsrc);
    float4 wr0 = *reinterpret_cast<const float4*>(wsrc[0]);
    float4 wr1 = *reinterpret_cast<const float4*>(wsrc[1]);
    float4 wr2 = *reinterpret_cast<const float4*>(wsrc[2]);
    float4 wr3 = *reinterpret_cast<const float4*>(wsrc[3]);

    for (int c = 0; c < NC; ++c) {
        __syncthreads();
        {
            const int k0 = sfi * 4;
            xs[k0+0][stok] = (double)xr.x;  xs[k0+1][stok] = (double)xr.y;
            xs[k0+2][stok] = (double)xr.z;  xs[k0+3][stok] = (double)xr.w;
            wt[k0+0][stok      ] = (double)wr0.x; wt[k0+1][stok      ] = (double)wr0.y;
            wt[k0+2][stok      ] = (double)wr0.z; wt[k0+3][stok      ] = (double)wr0.w;
            wt[k0+0][stok + 32 ] = (double)wr1.x; wt[k0+1][stok + 32 ] = (double)wr1.y;
            wt[k0+2][stok + 32 ] = (double)wr1.z; wt[k0+3][stok + 32 ] = (double)wr1.w;
            wt[k0+0][stok + 64 ] = (double)wr2.x; wt[k0+1][stok + 64 ] = (double)wr2.y;
            wt[k0+2][stok + 64 ] = (double)wr2.z; wt[k0+3][stok + 64 ] = (double)wr2.w;
            wt[k0+0][stok + 96 ] = (double)wr3.x; wt[k0+1][stok + 96 ] = (double)wr3.y;
            wt[k0+2][stok + 96 ] = (double)wr3.z; wt[k0+3][stok + 96 ] = (double)wr3.w;
        }
        __syncthreads();
        if (c + 1 < NC) {
            const int off = (c + 1) * DK;
            xr  = *reinterpret_cast<const float4*>(xsrc + off);
            wr0 = *reinterpret_cast<const float4*>(wsrc[0] + off);
            wr1 = *reinterpret_cast<const float4*>(wsrc[1] + off);
            wr2 = *reinterpret_cast<const float4*>(wsrc[2] + off);
            wr3 = *reinterpret_cast<const float4*>(wsrc[3] + off);
        }
        #pragma unroll 4
        for (int k = 0; k < DK; ++k) {
            const double2_t xv0 = *reinterpret_cast<const double2_t*>(&xs[k][tg * 4]);
            const double2_t xv1 = *reinterpret_cast<const double2_t*>(&xs[k][tg * 4 + 2]);
            const double2_t w0  = *reinterpret_cast<const double2_t*>(&wt[k][2 * eg]);
            const double2_t w1  = *reinterpret_cast<const double2_t*>(&wt[k][64 + 2 * eg]);
            const double xvv[4] = {xv0.x, xv0.y, xv1.x, xv1.y};
            #pragma unroll
            for (int t = 0; t < 4; ++t) {
                acc[t][0] = fma(xvv[t], w0.x, acc[t][0]);
                acc[t][1] = fma(xvv[t], w0.y, acc[t][1]);
                acc[t][2] = fma(xvv[t], w1.x, acc[t][2]);
                acc[t][3] = fma(xvv[t], w1.y, acc[t][3]);
            }
        }
    }
    __syncthreads();
    #pragma unroll
    for (int t = 0; t < 4; ++t) {
        double2_t lo = {acc[t][0], acc[t][1]};
        double2_t hi = {acc[t][2], acc[t][3]};
        *reinterpret_cast<double2_t*>(&zbuf[tg * 4 + t][2 * eg])      = lo;
        *reinterpret_cast<double2_t*>(&zbuf[tg * 4 + t][64 + 2 * eg]) = hi;
    }
    __syncthreads();

    const int wid  = tid >> 6;
    const int lane = tid & 63;
    for (int tt = 0; tt < 8; ++tt) {
        const int tok = wid * 8 + tt;
        const size_t gtok = (size_t)tok0 + tok;
        const double logit = zbuf[tok][lane];
        const double noisy = zbuf[tok][EE + lane];
        const double zv = (double)noise_u[gtok * EE + lane] * softplus64(noisy)
                          + logit + (double)bias[lane];
        double zw = zv;
        bool   sel = false;
        double m0  = 0.0;
        #pragma unroll
        for (int it = 0; it < KK; ++it) {
            double v  = zw;
            int    ix = lane;
            #pragma unroll
            for (int off = 32; off > 0; off >>= 1) {
                const double ov = __shfl_xor(v, off, 64);
                const int    oi = __shfl_xor(ix, off, 64);
                if (ov > v || (ov == v && oi < ix)) { v = ov; ix = oi; }
            }
            if (it == 0) m0 = v;
            if (lane == ix) { sel = true; zw = -INFINITY; }
            if (lane == 0) out_idx[gtok * KK + it] = (float)ix;
        }
        const double ex = sel ? exp(zv - m0) : 0.0;
        double den = ex;
        #pragma unroll
        for (int off = 32; off > 0; off >>= 1) den += __shfl_xor(den, off, 64);
        out_probs[gtok * EE + lane] = (float)(ex / den);
    }
}

__global__ void bias_kernel(const float* __restrict__ bias,
                            float* __restrict__ out_bias)
{
    const int e = threadIdx.x;
    if (e < EE) {
        const double load_violation = (double)(TT_TOTAL * KK) / EE
                                      - (double)(TT_TOTAL * KK);
        const double s = (load_violation > 0.0) ? 1.0
                         : ((load_violation < 0.0) ? -1.0 : 0.0);
        out_bias[e] = bias[e] + (float)(0.001 * s);
    }
}

extern "C" void kernel_launch(void* const* d_in, const int* in_sizes, int n_in,
                              void* d_out, int out_size, void* d_ws, size_t ws_size,
                              hipStream_t stream)
{
    const float* x       = (const float*)d_in[0];
    const float* Wr      = (const float*)d_in[1];
    const float* Wn      = (const float*)d_in[2];
    const float* bias    = (const float*)d_in[3];
    const float* noise_u = (const float*)d_in[4];

    float* out       = (float*)d_out;
    float* out_probs = out;
    float* out_idx   = out + (size_t)TT_TOTAL * EE;
    float* out_bias  = out + (size_t)TT_TOTAL * EE + (size_t)TT_TOTAL * KK;

    const size_t z1 = (size_t)TT_TOTAL * E2 * sizeof(double);   // 16 MiB

    if (ws_size >= 4 * z1) {
        double* zp = (double*)d_ws;
        gemm64_kernel<4><<<256 * 4, 256, 0, stream>>>(x, Wr, Wn, zp);
        topk2_kernel<4><<<TT_TOTAL / 32, 256, 0, stream>>>(zp, bias, noise_u,
                                                           out_probs, out_idx);
    } else if (ws_size >= 2 * z1) {
        double* zp = (double*)d_ws;
        gemm64_kernel<2><<<256 * 2, 256, 0, stream>>>(x, Wr, Wn, zp);
        topk2_kernel<2><<<TT_TOTAL / 32, 256, 0, stream>>>(zp, bias, noise_u,
                                                           out_probs, out_idx);
    } else if (ws_size >= z1) {
        double* z = (double*)d_ws;
        gemm_kernel<<<(TT_TOTAL / BT) * 2, 256, 0, stream>>>(x, Wr, Wn, z);
        topk2_kernel<1><<<TT_TOTAL / 32, 256, 0, stream>>>(z, bias, noise_u,
                                                           out_probs, out_idx);
    } else {
        router_kernel<<<TT_TOTAL / 32, 256, 0, stream>>>(
            x, Wr, Wn, bias, noise_u, out_probs, out_idx);
    }
    bias_kernel<<<1, 64, 0, stream>>>(bias, out_bias);
}

// Round 8
// 236.623 us; speedup vs baseline: 1.1753x; 1.1753x over previous
//
#include <hip/hip_runtime.h>
#include <math.h>

#define BB 4
#define SS 4096
#define DD 2048
#define EE 64
#define KK 8
#define TT_TOTAL (BB*SS)      // 16384 tokens
#define E2 128                // stacked outputs (Wr 0..63, Wn 64..127)
#define DK 32
#define NC (DD/DK)

typedef double double2_t __attribute__((ext_vector_type(2)));
typedef double double4_t __attribute__((ext_vector_type(4)));

__device__ __forceinline__ double softplus64(double x) {
    return fmax(x, 0.0) + log1p(exp(-fabs(x)));
}

// LDS column swizzle: involution on bits 1..3 keyed by bits 4..6.
__device__ __forceinline__ int SW(int c) {
    return c ^ (((c >> 4) & 7) << 1);
}

// =====================================================================
// Primary GEMM: block tile 128 tok x 128 out, thread tile 8x8, f64 LDS,
// DOUBLE-BUFFERED at half-depth chunks (DKH=16): one barrier per chunk,
// ds_writes overlap FMAs. Accumulation order identical to R6 (ascending
// k) -> zp bit-identical. grid = 128*KS, 256 threads, 2 blocks/CU.
// =====================================================================
#define DKH 16
#define ROW 130   // 128 cols + 2 pad (1040 B rows, 16B-aligned)

template<int KS>
__launch_bounds__(256, 2)
__global__ void gemm8d_kernel(const float* __restrict__ x,
                              const float* __restrict__ Wr,
                              const float* __restrict__ Wn,
                              double* __restrict__ zp)
{
    __shared__ __align__(16) double xs[2][DKH][ROW];   // 33280 B
    __shared__ __align__(16) double ws[2][DKH][ROW];   // 33280 B

    const int tid   = threadIdx.x;
    const int split = blockIdx.x % KS;
    const int bt    = blockIdx.x / KS;
    const int tok0  = bt * 128;
    const int kbase = split * (DD / KS);
    const int NCH   = (DD / KS) / DKH;                 // 32 at KS=4

    // ---- staging mapping: row = tid&127, k-half = tid>>7 (8 k each) ----
    const int srow = tid & 127;
    const int skh  = tid >> 7;            // 0/1 -> k 0..7 / 8..15
    const int scol = SW(srow);
    const float* xsrc = x + (size_t)(tok0 + srow) * DD + kbase + 8 * skh;
    const float* wsrc = ((srow < EE) ? Wr + (size_t)srow * DD
                                     : Wn + (size_t)(srow - EE) * DD)
                        + kbase + 8 * skh;

    // ---- compute mapping: toks {2tg2+e+32h}, outs {2og2+f+32g} ----
    const int og2 = tid & 15;
    const int tg2 = tid >> 4;
    int colx[4], colw[4];
    #pragma unroll
    for (int h = 0; h < 4; ++h) colx[h] = SW(2 * tg2 + 32 * h);
    #pragma unroll
    for (int g = 0; g < 4; ++g) colw[g] = SW(2 * og2 + 32 * g);

    double acc[8][8];
    #pragma unroll
    for (int i = 0; i < 8; ++i)
        #pragma unroll
        for (int j = 0; j < 8; ++j) acc[i][j] = 0.0;

    // staging registers (8 floats of x, 8 of W = current chunk's slice)
    float4 xa0, xa1, wa0, wa1;

    // prologue: chunk 0 -> regs -> buf0; chunk 1 -> regs
    xa0 = *reinterpret_cast<const float4*>(xsrc);
    xa1 = *reinterpret_cast<const float4*>(xsrc + 4);
    wa0 = *reinterpret_cast<const float4*>(wsrc);
    wa1 = *reinterpret_cast<const float4*>(wsrc + 4);
    {
        const int k0 = 8 * skh;
        xs[0][k0+0][scol] = (double)xa0.x;  xs[0][k0+1][scol] = (double)xa0.y;
        xs[0][k0+2][scol] = (double)xa0.z;  xs[0][k0+3][scol] = (double)xa0.w;
        xs[0][k0+4][scol] = (double)xa1.x;  xs[0][k0+5][scol] = (double)xa1.y;
        xs[0][k0+6][scol] = (double)xa1.z;  xs[0][k0+7][scol] = (double)xa1.w;
        ws[0][k0+0][scol] = (double)wa0.x;  ws[0][k0+1][scol] = (double)wa0.y;
        ws[0][k0+2][scol] = (double)wa0.z;  ws[0][k0+3][scol] = (double)wa0.w;
        ws[0][k0+4][scol] = (double)wa1.x;  ws[0][k0+5][scol] = (double)wa1.y;
        ws[0][k0+6][scol] = (double)wa1.z;  ws[0][k0+7][scol] = (double)wa1.w;
    }
    if (NCH > 1) {
        xa0 = *reinterpret_cast<const float4*>(xsrc + DKH);
        xa1 = *reinterpret_cast<const float4*>(xsrc + DKH + 4);
        wa0 = *reinterpret_cast<const float4*>(wsrc + DKH);
        wa1 = *reinterpret_cast<const float4*>(wsrc + DKH + 4);
    }
    __syncthreads();

    for (int c = 0; c < NCH; ++c) {
        const int b = c & 1;

        // stage regs (chunk c+1) -> other buffer; overlaps compute below
        if (c + 1 < NCH) {
            const int k0 = 8 * skh;
            xs[b^1][k0+0][scol] = (double)xa0.x;  xs[b^1][k0+1][scol] = (double)xa0.y;
            xs[b^1][k0+2][scol] = (double)xa0.z;  xs[b^1][k0+3][scol] = (double)xa0.w;
            xs[b^1][k0+4][scol] = (double)xa1.x;  xs[b^1][k0+5][scol] = (double)xa1.y;
            xs[b^1][k0+6][scol] = (double)xa1.z;  xs[b^1][k0+7][scol] = (double)xa1.w;
            ws[b^1][k0+0][scol] = (double)wa0.x;  ws[b^1][k0+1][scol] = (double)wa0.y;
            ws[b^1][k0+2][scol] = (double)wa0.z;  ws[b^1][k0+3][scol] = (double)wa0.w;
            ws[b^1][k0+4][scol] = (double)wa1.x;  ws[b^1][k0+5][scol] = (double)wa1.y;
            ws[b^1][k0+6][scol] = (double)wa1.z;  ws[b^1][k0+7][scol] = (double)wa1.w;
        }
        // prefetch chunk c+2 into regs (lands under compute)
        if (c + 2 < NCH) {
            const int off = (c + 2) * DKH;
            xa0 = *reinterpret_cast<const float4*>(xsrc + off);
            xa1 = *reinterpret_cast<const float4*>(xsrc + off + 4);
            wa0 = *reinterpret_cast<const float4*>(wsrc + off);
            wa1 = *reinterpret_cast<const float4*>(wsrc + off + 4);
        }

        // compute current buffer: per k, 8x ds_read_b128 + 64 f64 FMA
        #pragma unroll 4
        for (int k = 0; k < DKH; ++k) {
            double2_t xv[4], wv[4];
            #pragma unroll
            for (int h = 0; h < 4; ++h)
                xv[h] = *reinterpret_cast<const double2_t*>(&xs[b][k][colx[h]]);
            #pragma unroll
            for (int g = 0; g < 4; ++g)
                wv[g] = *reinterpret_cast<const double2_t*>(&ws[b][k][colw[g]]);
            #pragma unroll
            for (int h = 0; h < 4; ++h)
                #pragma unroll
                for (int e = 0; e < 2; ++e)
                    #pragma unroll
                    for (int g = 0; g < 4; ++g) {
                        acc[2*h+e][2*g+0] = fma(xv[h][e], wv[g][0], acc[2*h+e][2*g+0]);
                        acc[2*h+e][2*g+1] = fma(xv[h][e], wv[g][1], acc[2*h+e][2*g+1]);
                    }
        }
        __syncthreads();
    }

    // write partials: zp[split][tok][out]
    double* zbase = zp + (size_t)split * TT_TOTAL * E2;
    #pragma unroll
    for (int h = 0; h < 4; ++h)
        #pragma unroll
        for (int e = 0; e < 2; ++e) {
            const int tok = 2 * tg2 + e + 32 * h;
            double* row = zbase + (size_t)(tok0 + tok) * E2;
            #pragma unroll
            for (int g = 0; g < 4; ++g) {
                double2_t v = {acc[2*h+e][2*g+0], acc[2*h+e][2*g+1]};
                *reinterpret_cast<double2_t*>(&row[2 * og2 + 32 * g]) = v;
            }
        }
}

// =====================================================================
// topk over reduced partials (ascending split order = deterministic)
// =====================================================================
template<int KS>
__launch_bounds__(256, 4)
__global__ void topk2_kernel(const double* __restrict__ zp,
                             const float* __restrict__ bias,
                             const float* __restrict__ noise_u,
                             float* __restrict__ out_probs,
                             float* __restrict__ out_idx)
{
    const int tid  = threadIdx.x;
    const int wid  = tid >> 6;
    const int lane = tid & 63;
    const int tok0 = blockIdx.x * 32;

    for (int tt = 0; tt < 8; ++tt) {
        const int tok = tok0 + wid * 8 + tt;
        const size_t gtok = (size_t)tok;

        double logit = 0.0, noisy = 0.0;
        #pragma unroll
        for (int s = 0; s < KS; ++s) {
            const double* row = zp + (size_t)s * TT_TOTAL * E2 + (size_t)tok * E2;
            logit += row[lane];
            noisy += row[EE + lane];
        }
        const double zv = (double)noise_u[gtok * EE + lane] * softplus64(noisy)
                          + logit + (double)bias[lane];

        double zw = zv;
        bool   sel = false;
        double m0  = 0.0;
        #pragma unroll
        for (int it = 0; it < KK; ++it) {
            double v  = zw;
            int    ix = lane;
            #pragma unroll
            for (int off = 32; off > 0; off >>= 1) {
                const double ov = __shfl_xor(v, off, 64);
                const int    oi = __shfl_xor(ix, off, 64);
                if (ov > v || (ov == v && oi < ix)) { v = ov; ix = oi; }
            }
            if (it == 0) m0 = v;
            if (lane == ix) { sel = true; zw = -INFINITY; }
            if (lane == 0) out_idx[gtok * KK + it] = (float)ix;
        }

        const double ex = sel ? exp(zv - m0) : 0.0;
        double den = ex;
        #pragma unroll
        for (int off = 32; off > 0; off >>= 1) den += __shfl_xor(den, off, 64);

        out_probs[gtok * EE + lane] = (float)(ex / den);
    }
}

// =====================================================================
// Tier-B: verified R5 two-kernel path (16 MiB ws)
// =====================================================================
#define BT 32
#define XT 34
#define WT 66

__launch_bounds__(256, 4)
__global__ void gemm_kernel(const float* __restrict__ x,
                            const float* __restrict__ Wr,
                            const float* __restrict__ Wn,
                            double* __restrict__ zout)
{
    __shared__ __align__(16) double xs[DK][XT];
    __shared__ __align__(16) double ws[DK][WT];

    const int tid  = threadIdx.x;
    const int bt   = blockIdx.x >> 1;
    const int be   = blockIdx.x & 1;
    const int tok0 = bt * BT;
    const int e0   = be * 64;

    const int kk = tid & 31;
    const int tq = tid >> 5;
    const float* xsrc[4];
    const float* wsrc[8];
    #pragma unroll
    for (int j = 0; j < 4; ++j)
        xsrc[j] = x + (size_t)(tok0 + 4 * tq + j) * DD + kk;
    #pragma unroll
    for (int j = 0; j < 4; ++j) {
        const int e  = e0 + 4 * tq + j;
        const int e2 = e0 + 32 + 4 * tq + j;
        wsrc[j]     = ((e  < EE) ? Wr + (size_t)e * DD
                                 : Wn + (size_t)(e  - EE) * DD) + kk;
        wsrc[4 + j] = ((e2 < EE) ? Wr + (size_t)e2 * DD
                                 : Wn + (size_t)(e2 - EE) * DD) + kk;
    }

    const int og = tid & 15;
    const int tp = tid >> 4;

    double acc[2][4];
    #pragma unroll
    for (int t = 0; t < 2; ++t)
        #pragma unroll
        for (int i = 0; i < 4; ++i) acc[t][i] = 0.0;

    float xr[4], wr[8];
    #pragma unroll
    for (int j = 0; j < 4; ++j) xr[j] = xsrc[j][0];
    #pragma unroll
    for (int j = 0; j < 8; ++j) wr[j] = wsrc[j][0];

    for (int c = 0; c < NC; ++c) {
        __syncthreads();
        {
            double4_t xv = {(double)xr[0], (double)xr[1], (double)xr[2], (double)xr[3]};
            *reinterpret_cast<double4_t*>(&xs[kk][4 * tq]) = xv;
            double4_t w0 = {(double)wr[0], (double)wr[1], (double)wr[2], (double)wr[3]};
            *reinterpret_cast<double4_t*>(&ws[kk][4 * tq]) = w0;
            double4_t w1 = {(double)wr[4], (double)wr[5], (double)wr[6], (double)wr[7]};
            *reinterpret_cast<double4_t*>(&ws[kk][32 + 4 * tq]) = w1;
        }
        __syncthreads();
        if (c + 1 < NC) {
            const int off = (c + 1) * DK;
            #pragma unroll
            for (int j = 0; j < 4; ++j) xr[j] = xsrc[j][off];
            #pragma unroll
            for (int j = 0; j < 8; ++j) wr[j] = wsrc[j][off];
        }
        #pragma unroll 4
        for (int k = 0; k < DK; ++k) {
            const double2_t xv = *reinterpret_cast<const double2_t*>(&xs[k][2 * tp]);
            const double2_t w0 = *reinterpret_cast<const double2_t*>(&ws[k][2 * og]);
            const double2_t w1 = *reinterpret_cast<const double2_t*>(&ws[k][32 + 2 * og]);
            acc[0][0] = fma(xv.x, w0.x, acc[0][0]);
            acc[0][1] = fma(xv.x, w0.y, acc[0][1]);
            acc[0][2] = fma(xv.x, w1.x, acc[0][2]);
            acc[0][3] = fma(xv.x, w1.y, acc[0][3]);
            acc[1][0] = fma(xv.y, w0.x, acc[1][0]);
            acc[1][1] = fma(xv.y, w0.y, acc[1][1]);
            acc[1][2] = fma(xv.y, w1.x, acc[1][2]);
            acc[1][3] = fma(xv.y, w1.y, acc[1][3]);
        }
    }

    #pragma unroll
    for (int t = 0; t < 2; ++t) {
        const size_t base = (size_t)(tok0 + 2 * tp + t) * E2 + e0;
        double2_t lo = {acc[t][0], acc[t][1]};
        double2_t hi = {acc[t][2], acc[t][3]};
        *reinterpret_cast<double2_t*>(&zout[base + 2 * og])      = lo;
        *reinterpret_cast<double2_t*>(&zout[base + 32 + 2 * og]) = hi;
    }
}

// =====================================================================
// Tier-C: verified R4 monolithic kernel
// =====================================================================
#define F_XT 34
#define F_WR 130
#define F_ZR 130
#define F_SMEM ((DK*F_XT + DK*F_WR)*8)

__launch_bounds__(256, 3)
__global__ void router_kernel(const float* __restrict__ x,
                              const float* __restrict__ Wr,
                              const float* __restrict__ Wn,
                              const float* __restrict__ bias,
                              const float* __restrict__ noise_u,
                              float* __restrict__ out_probs,
                              float* __restrict__ out_idx)
{
    __shared__ __align__(16) char smem_raw[F_SMEM];
    double (*xs)[F_XT] = reinterpret_cast<double(*)[F_XT]>(smem_raw);
    double (*wt)[F_WR] = reinterpret_cast<double(*)[F_WR]>(smem_raw + DK*F_XT*8);
    double (*zbuf)[F_ZR] = reinterpret_cast<double(*)[F_ZR]>(smem_raw);

    const int tid  = threadIdx.x;
    const int tok0 = blockIdx.x * 32;
    const int stok = tid >> 3;
    const int sfi  = tid & 7;
    const float* xsrc = x + (size_t)(tok0 + stok) * DD + sfi * 4;
    const float* wsrc[4];
    #pragma unroll
    for (int it = 0; it < 4; ++it) {
        const int r = it * 32 + stok;
        wsrc[it] = ((r < EE) ? (Wr + (size_t)r * DD)
                             : (Wn + (size_t)(r - EE) * DD)) + sfi * 4;
    }
    const int tg = tid >> 5;
    const int eg = tid & 31;

    double acc[4][4];
    #pragma unroll
    for (int t = 0; t < 4; ++t)
        #pragma unroll
        for (int i = 0; i < 4; ++i) acc[t][i] = 0.0;

    float4 xr  = *reinterpret_cast<const float4*>(xsrc);
    float4 wr0 = *reinterpret_cast<const float4*>(wsrc[0]);
    float4 wr1 = *reinterpret_cast<const float4*>(wsrc[1]);
    float4 wr2 = *reinterpret_cast<const float4*>(wsrc[2]);
    float4 wr3 = *reinterpret_cast<const float4*>(wsrc[3]);

    for (int c = 0; c < NC; ++c) {
        __syncthreads();
        {
            const int k0 = sfi * 4;
            xs[k0+0][stok] = (double)xr.x;  xs[k0+1][stok] = (double)xr.y;
            xs[k0+2][stok] = (double)xr.z;  xs[k0+3][stok] = (double)xr.w;
            wt[k0+0][stok      ] = (double)wr0.x; wt[k0+1][stok      ] = (double)wr0.y;
            wt[k0+2][stok      ] = (double)wr0.z; wt[k0+3][stok      ] = (double)wr0.w;
            wt[k0+0][stok + 32 ] = (double)wr1.x; wt[k0+1][stok + 32 ] = (double)wr1.y;
            wt[k0+2][stok + 32 ] = (double)wr1.z; wt[k0+3][stok + 32 ] = (double)wr1.w;
            wt[k0+0][stok + 64 ] = (double)wr2.x; wt[k0+1][stok + 64 ] = (double)wr2.y;
            wt[k0+2][stok + 64 ] = (double)wr2.z; wt[k0+3][stok + 64 ] = (double)wr2.w;
            wt[k0+0][stok + 96 ] = (double)wr3.x; wt[k0+1][stok + 96 ] = (double)wr3.y;
            wt[k0+2][stok + 96 ] = (double)wr3.z; wt[k0+3][stok + 96 ] = (double)wr3.w;
        }
        __syncthreads();
        if (c + 1 < NC) {
            const int off = (c + 1) * DK;
            xr  = *reinterpret_cast<const float4*>(xsrc + off);
            wr0 = *reinterpret_cast<const float4*>(wsrc[0] + off);
            wr1 = *reinterpret_cast<const float4*>(wsrc[1] + off);
            wr2 = *reinterpret_cast<const float4*>(wsrc[2] + off);
            wr3 = *reinterpret_cast<const float4*>(wsrc[3] + off);
        }
        #pragma unroll 4
        for (int k = 0; k < DK; ++k) {
            const double2_t xv0 = *reinterpret_cast<const double2_t*>(&xs[k][tg * 4]);
            const double2_t xv1 = *reinterpret_cast<const double2_t*>(&xs[k][tg * 4 + 2]);
            const double2_t w0  = *reinterpret_cast<const double2_t*>(&wt[k][2 * eg]);
            const double2_t w1  = *reinterpret_cast<const double2_t*>(&wt[k][64 + 2 * eg]);
            const double xvv[4] = {xv0.x, xv0.y, xv1.x, xv1.y};
            #pragma unroll
            for (int t = 0; t < 4; ++t) {
                acc[t][0] = fma(xvv[t], w0.x, acc[t][0]);
                acc[t][1] = fma(xvv[t], w0.y, acc[t][1]);
                acc[t][2] = fma(xvv[t], w1.x, acc[t][2]);
                acc[t][3] = fma(xvv[t], w1.y, acc[t][3]);
            }
        }
    }
    __syncthreads();
    #pragma unroll
    for (int t = 0; t < 4; ++t) {
        double2_t lo = {acc[t][0], acc[t][1]};
        double2_t hi = {acc[t][2], acc[t][3]};
        *reinterpret_cast<double2_t*>(&zbuf[tg * 4 + t][2 * eg])      = lo;
        *reinterpret_cast<double2_t*>(&zbuf[tg * 4 + t][64 + 2 * eg]) = hi;
    }
    __syncthreads();

    const int wid  = tid >> 6;
    const int lane = tid & 63;
    for (int tt = 0; tt < 8; ++tt) {
        const int tok = wid * 8 + tt;
        const size_t gtok = (size_t)tok0 + tok;
        const double logit = zbuf[tok][lane];
        const double noisy = zbuf[tok][EE + lane];
        const double zv = (double)noise_u[gtok * EE + lane] * softplus64(noisy)
                          + logit + (double)bias[lane];
        double zw = zv;
        bool   sel = false;
        double m0  = 0.0;
        #pragma unroll
        for (int it = 0; it < KK; ++it) {
            double v  = zw;
            int    ix = lane;
            #pragma unroll
            for (int off = 32; off > 0; off >>= 1) {
                const double ov = __shfl_xor(v, off, 64);
                const int    oi = __shfl_xor(ix, off, 64);
                if (ov > v || (ov == v && oi < ix)) { v = ov; ix = oi; }
            }
            if (it == 0) m0 = v;
            if (lane == ix) { sel = true; zw = -INFINITY; }
            if (lane == 0) out_idx[gtok * KK + it] = (float)ix;
        }
        const double ex = sel ? exp(zv - m0) : 0.0;
        double den = ex;
        #pragma unroll
        for (int off = 32; off > 0; off >>= 1) den += __shfl_xor(den, off, 64);
        out_probs[gtok * EE + lane] = (float)(ex / den);
    }
}

__global__ void bias_kernel(const float* __restrict__ bias,
                            float* __restrict__ out_bias)
{
    const int e = threadIdx.x;
    if (e < EE) {
        const double load_violation = (double)(TT_TOTAL * KK) / EE
                                      - (double)(TT_TOTAL * KK);
        const double s = (load_violation > 0.0) ? 1.0
                         : ((load_violation < 0.0) ? -1.0 : 0.0);
        out_bias[e] = bias[e] + (float)(0.001 * s);
    }
}

extern "C" void kernel_launch(void* const* d_in, const int* in_sizes, int n_in,
                              void* d_out, int out_size, void* d_ws, size_t ws_size,
                              hipStream_t stream)
{
    const float* x       = (const float*)d_in[0];
    const float* Wr      = (const float*)d_in[1];
    const float* Wn      = (const float*)d_in[2];
    const float* bias    = (const float*)d_in[3];
    const float* noise_u = (const float*)d_in[4];

    float* out       = (float*)d_out;
    float* out_probs = out;
    float* out_idx   = out + (size_t)TT_TOTAL * EE;
    float* out_bias  = out + (size_t)TT_TOTAL * EE + (size_t)TT_TOTAL * KK;

    const size_t z1 = (size_t)TT_TOTAL * E2 * sizeof(double);   // 16 MiB

    if (ws_size >= 4 * z1) {
        double* zp = (double*)d_ws;
        gemm8d_kernel<4><<<128 * 4, 256, 0, stream>>>(x, Wr, Wn, zp);
        topk2_kernel<4><<<TT_TOTAL / 32, 256, 0, stream>>>(zp, bias, noise_u,
                                                           out_probs, out_idx);
    } else if (ws_size >= 2 * z1) {
        double* zp = (double*)d_ws;
        gemm8d_kernel<2><<<128 * 2, 256, 0, stream>>>(x, Wr, Wn, zp);
        topk2_kernel<2><<<TT_TOTAL / 32, 256, 0, stream>>>(zp, bias, noise_u,
                                                           out_probs, out_idx);
    } else if (ws_size >= z1) {
        double* z = (double*)d_ws;
        gemm_kernel<<<(TT_TOTAL / BT) * 2, 256, 0, stream>>>(x, Wr, Wn, z);
        topk2_kernel<1><<<TT_TOTAL / 32, 256, 0, stream>>>(z, bias, noise_u,
                                                           out_probs, out_idx);
    } else {
        router_kernel<<<TT_TOTAL / 32, 256, 0, stream>>>(
            x, Wr, Wn, bias, noise_u, out_probs, out_idx);
    }
    bias_kernel<<<1, 64, 0, stream>>>(bias, out_bias);
}